// Round 4
// baseline (360.733 us; speedup 1.0000x reference)
//
#include <hip/hip_runtime.h>
#include <math.h>

// ============================================================================
// Attention block (B=8, C=512, H=W=32, nh=8, hd=64) via bf16x3 MFMA.
// Round 4: attention = round-3 structure (single barrier/iter, double-buffered
// K/V, hi/lo planes, single-bf16 V, stride-68 LDS) but fixed execution env:
//   - 256-thread blocks, 64-query tiles -> grid 512 = 2 independent
//     barrier-domains per CU (phases interleave across blocks)
//   - __launch_bounds__(256,2) -> VGPR cap 256 (r3's 512-thread launch starved
//     the allocator to 56 VGPRs -> remat/spill in the K-loop critical path)
//   - LDS 60,928 B < 64 KB (r3's 69.6 KB forced 1 block/CU + a 30ms outlier)
// GEMM cores unchanged from round 2.
// ============================================================================

typedef unsigned int u32;
typedef float  f32x4 __attribute__((ext_vector_type(4)));
typedef short  s16x8 __attribute__((ext_vector_type(8)));
typedef unsigned short u16x4 __attribute__((ext_vector_type(4)));
typedef unsigned int   u32x4 __attribute__((ext_vector_type(4)));

#define MFMA16(a, b, c) __builtin_amdgcn_mfma_f32_16x16x32_bf16(a, b, c, 0, 0, 0)

// split fp32 -> (hi bf16 << 16) | lo bf16.  hi = truncation, lo = RNE(f - hi)
__device__ __forceinline__ u32 splitpack(float f) {
    u32 b = __float_as_uint(f);
    u32 hb = b & 0xFFFF0000u;
    float lf = f - __uint_as_float(hb);
    u32 lb = __float_as_uint(lf);
    u32 lr = (lb + 0x7FFFu + ((lb >> 16) & 1u)) >> 16;
    return hb | (lr & 0xFFFFu);
}
__device__ __forceinline__ ushort f2bf(float f) {  // RNE fp32->bf16
    u32 b = __float_as_uint(f);
    return (ushort)((b + 0x7FFFu + ((b >> 16) & 1u)) >> 16);
}
__device__ __forceinline__ void unpack4(u32x4 v, u16x4& hi, u16x4& lo) {
    hi[0] = (ushort)(v.x >> 16); hi[1] = (ushort)(v.y >> 16);
    hi[2] = (ushort)(v.z >> 16); hi[3] = (ushort)(v.w >> 16);
    lo[0] = (ushort)v.x; lo[1] = (ushort)v.y;
    lo[2] = (ushort)v.z; lo[3] = (ushort)v.w;
}

// ---------------------------------------------------------------------------
// split_w: both weight matrices -> hi/lo bf16 planes, same [o][c] layout.
// ---------------------------------------------------------------------------
__global__ __launch_bounds__(256) void split_w(const float* __restrict__ wq,
                                               const float* __restrict__ wp,
                                               ushort* __restrict__ wq_h, ushort* __restrict__ wq_l,
                                               ushort* __restrict__ wp_h, ushort* __restrict__ wp_l) {
    size_t base = ((size_t)blockIdx.x * 256 + threadIdx.x) * 4;
    const float* src; ushort *dh, *dl; size_t off;
    if (base < 786432) { src = wq; dh = wq_h; dl = wq_l; off = base; }
    else               { src = wp; dh = wp_h; dl = wp_l; off = base - 786432; }
    f32x4 v = *(const f32x4*)(src + off);
    u16x4 hi, lo;
#pragma unroll
    for (int e = 0; e < 4; e++) { u32 pk = splitpack(v[e]); hi[e] = (ushort)(pk >> 16); lo[e] = (ushort)pk; }
    *(u16x4*)(dh + off) = hi;
    *(u16x4*)(dl + off) = lo;
}

// ---------------------------------------------------------------------------
// split_x: x[b][c][n] fp32 -> xt hi/lo [bl][n][c] bf16 (64x64 tile transpose).
// ---------------------------------------------------------------------------
__global__ __launch_bounds__(256) void split_x(const float* __restrict__ x,
                                               ushort* __restrict__ xh, ushort* __restrict__ xl,
                                               int bbase) {
    __shared__ __align__(16) ushort Th[64 * 72];
    __shared__ __align__(16) ushort Tl[64 * 72];
    const int t = threadIdx.x;
    const int n0 = blockIdx.x * 64, c0 = blockIdx.y * 64, bz = blockIdx.z;
    const int b = bbase + bz;
    const int c = t >> 2, nseg = (t & 3) * 4;
    const float* src = x + ((size_t)b * 512 + c0 + c) * 1024 + n0;
#pragma unroll
    for (int i = 0; i < 4; i++) {
        f32x4 v = *(const f32x4*)(src + nseg + i * 16);
#pragma unroll
        for (int e = 0; e < 4; e++) {
            u32 pk = splitpack(v[e]);
            int nl = nseg + i * 16 + e;
            Th[nl * 72 + c] = (ushort)(pk >> 16);
            Tl[nl * 72 + c] = (ushort)pk;
        }
    }
    __syncthreads();
#pragma unroll
    for (int i = 0; i < 2; i++) {
        int nl = i * 32 + (t >> 3);
        int u = t & 7;
        s16x8 vh = *(const s16x8*)(Th + nl * 72 + u * 8);
        s16x8 vl = *(const s16x8*)(Tl + nl * 72 + u * 8);
        size_t go = ((size_t)bz * 1024 + n0 + nl) * 512 + c0 + u * 8;
        *(s16x8*)(xh + go) = vh;
        *(s16x8*)(xl + go) = vl;
    }
}

// ---------------------------------------------------------------------------
// Shared bf16x3 GEMM mainloop: 128x128 tile, BK=32, reg-prefetched staging.
// acc[Mt][Nt]: D rows o = ohalf*64+Mt*16+quad*4+r, cols n = nhalf*64+Nt*16+l15.
// ---------------------------------------------------------------------------
__device__ __forceinline__ void gemm_core(
    const ushort* __restrict__ Ah_g, const ushort* __restrict__ Al_g, int arow0,
    const ushort* __restrict__ Bh_g, const ushort* __restrict__ Bl_g, size_t brow0,
    ushort* smem, f32x4 (&acc)[4][4]) {
    const int t = threadIdx.x;
    ushort* As_h = smem;
    ushort* As_l = smem + 5120;
    ushort* Bs_h = smem + 10240;
    ushort* Bs_l = smem + 15360;
    const int ro = t >> 1, cs = (t & 1) << 4;
    const size_t ga = (size_t)(arow0 + ro) * 512 + cs;
    const size_t gb = (brow0 + ro) * 512 + cs;
    const int l15 = t & 15, quad = (t >> 4) & 3, wv = t >> 6;
    const int lra = (((wv >> 1) * 64) + l15) * 40 + quad * 8;
    const int lrb = (((wv & 1) * 64) + l15) * 40 + quad * 8;
    const int lw = ro * 40 + cs;

    s16x8 vah0 = *(const s16x8*)(Ah_g + ga),     vah1 = *(const s16x8*)(Ah_g + ga + 8);
    s16x8 val0 = *(const s16x8*)(Al_g + ga),     val1 = *(const s16x8*)(Al_g + ga + 8);
    s16x8 vbh0 = *(const s16x8*)(Bh_g + gb),     vbh1 = *(const s16x8*)(Bh_g + gb + 8);
    s16x8 vbl0 = *(const s16x8*)(Bl_g + gb),     vbl1 = *(const s16x8*)(Bl_g + gb + 8);

    for (int k0 = 0; k0 < 512; k0 += 32) {
        __syncthreads();
        *(s16x8*)(As_h + lw) = vah0; *(s16x8*)(As_h + lw + 8) = vah1;
        *(s16x8*)(As_l + lw) = val0; *(s16x8*)(As_l + lw + 8) = val1;
        *(s16x8*)(Bs_h + lw) = vbh0; *(s16x8*)(Bs_h + lw + 8) = vbh1;
        *(s16x8*)(Bs_l + lw) = vbl0; *(s16x8*)(Bs_l + lw + 8) = vbl1;
        const int kn = (k0 + 32) & 511;  // wraps to 0 on last iter (discarded)
        vah0 = *(const s16x8*)(Ah_g + ga + kn); vah1 = *(const s16x8*)(Ah_g + ga + kn + 8);
        val0 = *(const s16x8*)(Al_g + ga + kn); val1 = *(const s16x8*)(Al_g + ga + kn + 8);
        vbh0 = *(const s16x8*)(Bh_g + gb + kn); vbh1 = *(const s16x8*)(Bh_g + gb + kn + 8);
        vbl0 = *(const s16x8*)(Bl_g + gb + kn); vbl1 = *(const s16x8*)(Bl_g + gb + kn + 8);
        __syncthreads();
        s16x8 ah[4], al[4], bh[4], bl[4];
#pragma unroll
        for (int Mt = 0; Mt < 4; Mt++) {
            ah[Mt] = *(const s16x8*)(As_h + lra + Mt * 640);
            al[Mt] = *(const s16x8*)(As_l + lra + Mt * 640);
        }
#pragma unroll
        for (int Nt = 0; Nt < 4; Nt++) {
            bh[Nt] = *(const s16x8*)(Bs_h + lrb + Nt * 640);
            bl[Nt] = *(const s16x8*)(Bs_l + lrb + Nt * 640);
        }
#pragma unroll
        for (int Mt = 0; Mt < 4; Mt++)
#pragma unroll
            for (int Nt = 0; Nt < 4; Nt++) {
                acc[Mt][Nt] = MFMA16(ah[Mt], bh[Nt], acc[Mt][Nt]);
                acc[Mt][Nt] = MFMA16(ah[Mt], bl[Nt], acc[Mt][Nt]);
                acc[Mt][Nt] = MFMA16(al[Mt], bh[Nt], acc[Mt][Nt]);
            }
    }
    __syncthreads();  // LDS free for epilogue reuse
}

// ---------------------------------------------------------------------------
// QKV GEMM. o-halves (64 rows) align exactly to q/k/v roles: g = ot*2+ohalf,
// role = g%3 (0=q,1=k,2=v), head = g/3.  Q/K -> LDS transpose -> hi/lo bf16
// planes [b][h][n][d]; V -> single bf16 plane [b][h][d][n].
// ---------------------------------------------------------------------------
__global__ __launch_bounds__(256) void gemm_qkv(
    const ushort* __restrict__ wq_h, const ushort* __restrict__ wq_l,
    const ushort* __restrict__ xt_h, const ushort* __restrict__ xt_l,
    ushort* __restrict__ qhT, ushort* __restrict__ qlT,
    ushort* __restrict__ khT, ushort* __restrict__ klT,
    ushort* __restrict__ vbT) {
    __shared__ __align__(16) ushort smem[20480];
    f32x4 acc[4][4];
#pragma unroll
    for (int i = 0; i < 4; i++)
#pragma unroll
        for (int j = 0; j < 4; j++) acc[i][j] = (f32x4)0.0f;

    const int n0 = blockIdx.x * 128, o0 = blockIdx.y * 128, bz = blockIdx.z;
    gemm_core(wq_h, wq_l, o0, xt_h, xt_l, (size_t)bz * 1024 + n0, smem, acc);

    const int t = threadIdx.x;
    const int l15 = t & 15, quad = (t >> 4) & 3, wv = t >> 6, lane = t & 63;
    const int g = blockIdx.y * 2 + (wv >> 1);
    const int role = g % 3, head = g / 3;
    const int nh = (wv & 1) * 64;
    const size_t hb = (size_t)bz * 8 + head;
    const float scale = (role == 0) ? 0.125f : 1.0f;

    if (role < 2) {
        ushort* dh = (role == 0) ? qhT : khT;
        ushort* dl = (role == 0) ? qlT : klT;
        u32* T = (u32*)smem + wv * 2304;             // per-wave [64 n][36] u32
        const size_t rowbase = hb * 1024 + n0 + nh;  // pixel row index
#pragma unroll
        for (int sp = 0; sp < 2; sp++) {
#pragma unroll
            for (int Mti = 0; Mti < 2; Mti++)
#pragma unroll
                for (int Nt = 0; Nt < 4; Nt++) {
                    f32x4 v = acc[sp * 2 + Mti][Nt];
                    u32x4 pix;
#pragma unroll
                    for (int r = 0; r < 4; r++) pix[r] = splitpack(v[r] * scale);
                    *(u32x4*)(T + (Nt * 16 + l15) * 36 + Mti * 16 + quad * 4) = pix;
                }
            asm volatile("s_waitcnt lgkmcnt(0)" ::: "memory");
#pragma unroll
            for (int i = 0; i < 8; i++) {
                int nl = i * 8 + (lane >> 3);
                u32x4 vv = *(const u32x4*)(T + nl * 36 + (lane & 7) * 4);
                u16x4 hi, lo; unpack4(vv, hi, lo);
                size_t go = (rowbase + nl) * 64 + sp * 32 + (lane & 7) * 4;
                *(u16x4*)(dh + go) = hi;
                *(u16x4*)(dl + go) = lo;
            }
            asm volatile("s_waitcnt lgkmcnt(0)" ::: "memory");
        }
    } else {
        const size_t vb2 = hb * 64 * 1024 + (size_t)(n0 + nh);
#pragma unroll
        for (int Mt = 0; Mt < 4; Mt++)
#pragma unroll
            for (int Nt = 0; Nt < 4; Nt++)
#pragma unroll
                for (int r = 0; r < 4; r++)
                    vbT[vb2 + (size_t)(Mt * 16 + quad * 4 + r) * 1024 + Nt * 16 + l15] =
                        f2bf(acc[Mt][Nt][r]);
    }
}

// ---------------------------------------------------------------------------
// Proj GEMM: out fp32 + bias, direct C/D stores.
// ---------------------------------------------------------------------------
__global__ __launch_bounds__(256) void gemm_proj(
    const ushort* __restrict__ wp_h, const ushort* __restrict__ wp_l,
    const ushort* __restrict__ ht_h, const ushort* __restrict__ ht_l,
    const float* __restrict__ bias, float* __restrict__ out) {
    __shared__ __align__(16) ushort smem[20480];
    f32x4 acc[4][4];
#pragma unroll
    for (int i = 0; i < 4; i++)
#pragma unroll
        for (int j = 0; j < 4; j++) acc[i][j] = (f32x4)0.0f;

    const int n0 = blockIdx.x * 128, o0 = blockIdx.y * 128, bz = blockIdx.z;
    gemm_core(wp_h, wp_l, o0, ht_h, ht_l, (size_t)bz * 1024 + n0, smem, acc);

    const int t = threadIdx.x;
    const int l15 = t & 15, quad = (t >> 4) & 3, wv = t >> 6;
#pragma unroll
    for (int Mt = 0; Mt < 4; Mt++)
#pragma unroll
        for (int Nt = 0; Nt < 4; Nt++) {
            int ob = o0 + (wv >> 1) * 64 + Mt * 16 + quad * 4;
            int nn = n0 + (wv & 1) * 64 + Nt * 16 + l15;
#pragma unroll
            for (int r = 0; r < 4; r++)
                out[((size_t)bz * 512 + ob + r) * 1024 + nn] = acc[Mt][Nt][r] + bias[ob + r];
        }
}

// ---------------------------------------------------------------------------
// Flash attention, round 4.  256 threads (4 waves), one (b,h) + 64 queries
// per block -> grid 512 = 2 blocks/CU.  K hi/lo + V bf16 double-buffered in
// LDS; ONE barrier per iter (Ps is per-wave-private).  Strides 68 ushort
// (2-way bank aliasing = free).
// LDS map (ushort idx): Kh[2]@0/4352, Kl[2]@8704/13056, Vb[2]@17408/21760,
// Ps[64][68]@26112.  Total 30464 ushort = 60,928 B (< 64 KB).
// ---------------------------------------------------------------------------
__global__ __launch_bounds__(256, 2) void attn_mfma(
    const ushort* __restrict__ qhT, const ushort* __restrict__ qlT,
    const ushort* __restrict__ khT, const ushort* __restrict__ klT,
    const ushort* __restrict__ vbT,
    ushort* __restrict__ ht_h, ushort* __restrict__ ht_l, int bbase) {
    __shared__ __align__(16) ushort sm[30464];
    const int t = threadIdx.x;
    const int qt = blockIdx.x, bh = blockIdx.y;
    const int bl = bh >> 3, h = bh & 7;
    const int m0 = qt * 64;
    const size_t hb = (size_t)bl * 8 + h;
    const int l15 = t & 15, quad = (t >> 4) & 3, wv = t >> 6;  // wv 0..3
    const int row0 = t >> 3, seg = t & 7;                      // row0 0..31
    ushort* Ps = sm + 26112;

    // Persistent Q fragments (pre-scaled by 0.125); wave owns m = wv*16+l15
    s16x8 qfh[2], qfl[2];
    {
        const size_t qb = (hb * 1024 + m0 + wv * 16 + l15) * 64 + quad * 8;
        qfh[0] = *(const s16x8*)(qhT + qb);
        qfh[1] = *(const s16x8*)(qhT + qb + 32);
        qfl[0] = *(const s16x8*)(qlT + qb);
        qfl[1] = *(const s16x8*)(qlT + qb + 32);
    }

    // Staging: 256 threads x 2 chunks cover 64 rows x 64 cols per plane.
    // K plane [n][d]: row = n (key), V plane [d][n]: row = d.
    const size_t kg0 = (hb * 1024 + row0) * 64 + seg * 8;  // +i*2048, +kt*4096
    const size_t vg0 = (hb * 64 + row0) * 1024 + seg * 8;  // +i*32768, +kt*64
    const int lw0 = row0 * 68 + seg * 8;                   // +i*2176

    // Prologue: stage kt=0 into buffer 0
#pragma unroll
    for (int i = 0; i < 2; i++) {
        s16x8 k0h = *(const s16x8*)(khT + kg0 + i * 2048);
        s16x8 k0l = *(const s16x8*)(klT + kg0 + i * 2048);
        s16x8 v0  = *(const s16x8*)(vbT + vg0 + i * 32768);
        *(s16x8*)(sm + lw0 + i * 2176) = k0h;
        *(s16x8*)(sm + 8704 + lw0 + i * 2176) = k0l;
        *(s16x8*)(sm + 17408 + lw0 + i * 2176) = v0;
    }
    f32x4 O[4];
#pragma unroll
    for (int i = 0; i < 4; i++) O[i] = (f32x4)0.0f;
    float mrun = -3.0e38f, lrun = 0.f;
    __syncthreads();

    for (int kt = 0; kt < 16; kt++) {
        const int cur = kt & 1, nxt = cur ^ 1;
        const int ktn = (kt + 1) & 15;  // wraps; last-iter prefetch discarded
        // Prefetch next K/V tile into regs (overlaps all compute below)
        s16x8 rkh[2], rkl[2], rv[2];
#pragma unroll
        for (int i = 0; i < 2; i++) {
            rkh[i] = *(const s16x8*)(khT + kg0 + i * 2048 + (size_t)ktn * 4096);
            rkl[i] = *(const s16x8*)(klT + kg0 + i * 2048 + (size_t)ktn * 4096);
            rv[i]  = *(const s16x8*)(vbT + vg0 + i * 32768 + ktn * 64);
        }

        const ushort* Khc = sm + cur * 4352;
        const ushort* Klc = sm + 8704 + cur * 4352;
        const ushort* Vbc = sm + 17408 + cur * 4352;

        // S = K^T Q  (D: row nk = Mt*16+quad*4+r, col m = wv*16+l15)
        f32x4 S[4];
#pragma unroll
        for (int i = 0; i < 4; i++) S[i] = (f32x4)0.0f;
#pragma unroll
        for (int ks = 0; ks < 2; ks++) {
            s16x8 kh[4], kl[4];
#pragma unroll
            for (int Mt = 0; Mt < 4; Mt++) {
                kh[Mt] = *(const s16x8*)(Khc + (Mt * 16 + l15) * 68 + ks * 32 + quad * 8);
                kl[Mt] = *(const s16x8*)(Klc + (Mt * 16 + l15) * 68 + ks * 32 + quad * 8);
            }
#pragma unroll
            for (int Mt = 0; Mt < 4; Mt++) {
                S[Mt] = MFMA16(kh[Mt], qfh[ks], S[Mt]);
                S[Mt] = MFMA16(kh[Mt], qfl[ks], S[Mt]);
                S[Mt] = MFMA16(kl[Mt], qfh[ks], S[Mt]);
            }
        }
        // Online softmax over nk for this lane's column m
        float tm = -3.0e38f;
#pragma unroll
        for (int Mt = 0; Mt < 4; Mt++)
#pragma unroll
            for (int r = 0; r < 4; r++) tm = fmaxf(tm, S[Mt][r]);
        tm = fmaxf(tm, __shfl_xor(tm, 16));
        tm = fmaxf(tm, __shfl_xor(tm, 32));
        const float mnew = fmaxf(mrun, tm);
        const float alpha = __expf(mrun - mnew);
        float ts = 0.f;
#pragma unroll
        for (int Mt = 0; Mt < 4; Mt++)
#pragma unroll
            for (int r = 0; r < 4; r++) {
                float p = __expf(S[Mt][r] - mnew);
                S[Mt][r] = p;
                ts += p;
            }
        ts += __shfl_xor(ts, 16);
        ts += __shfl_xor(ts, 32);
        lrun = lrun * alpha + ts;
        mrun = mnew;
        // Write P (bf16) to per-wave-private LDS rows [m][nk] — no barrier
#pragma unroll
        for (int Mt = 0; Mt < 4; Mt++) {
            u16x4 pb;
#pragma unroll
            for (int r = 0; r < 4; r++) pb[r] = f2bf(S[Mt][r]);
            *(u16x4*)(Ps + (wv * 16 + l15) * 68 + Mt * 16 + quad * 4) = pb;
        }
        // O = O*alpha + V @ P
#pragma unroll
        for (int Mt = 0; Mt < 4; Mt++) O[Mt] *= alpha;
#pragma unroll
        for (int ks = 0; ks < 2; ks++) {
            s16x8 vf[4];
#pragma unroll
            for (int Mt = 0; Mt < 4; Mt++)
                vf[Mt] = *(const s16x8*)(Vbc + (Mt * 16 + l15) * 68 + ks * 32 + quad * 8);
            s16x8 pf = *(const s16x8*)(Ps + (wv * 16 + l15) * 68 + ks * 32 + quad * 8);
#pragma unroll
            for (int Mt = 0; Mt < 4; Mt++) O[Mt] = MFMA16(vf[Mt], pf, O[Mt]);
        }
        // Stage next tile into the other buffer, then the single barrier
#pragma unroll
        for (int i = 0; i < 2; i++) {
            *(s16x8*)(sm + nxt * 4352 + lw0 + i * 2176) = rkh[i];
            *(s16x8*)(sm + 8704 + nxt * 4352 + lw0 + i * 2176) = rkl[i];
            *(s16x8*)(sm + 17408 + nxt * 4352 + lw0 + i * 2176) = rv[i];
        }
        __syncthreads();
    }

    // Epilogue: O /= l, split hi/lo, LDS gather -> coalesced hT stores
    ushort* OLh = sm;          // [64][72]
    ushort* OLl = sm + 4608;
    const float linv = 1.f / lrun;
#pragma unroll
    for (int Mt = 0; Mt < 4; Mt++) {
        u16x4 hi, lo;
#pragma unroll
        for (int r = 0; r < 4; r++) {
            u32 pk = splitpack(O[Mt][r] * linv);
            hi[r] = (ushort)(pk >> 16);
            lo[r] = (ushort)pk;
        }
        const int m = wv * 16 + l15;
        *(u16x4*)(OLh + m * 72 + Mt * 16 + quad * 4) = hi;
        *(u16x4*)(OLl + m * 72 + Mt * 16 + quad * 4) = lo;
    }
    __syncthreads();
    const size_t ob = (size_t)(bbase + bl) * 1024 + m0;
#pragma unroll
    for (int i = 0; i < 2; i++) {
        const int m = i * 32 + (t >> 3);
        const int u = t & 7;
        s16x8 vh2 = *(const s16x8*)(OLh + m * 72 + u * 8);
        s16x8 vl2 = *(const s16x8*)(OLl + m * 72 + u * 8);
        size_t go = (ob + m) * 512 + h * 64 + u * 8;
        *(s16x8*)(ht_h + go) = vh2;
        *(s16x8*)(ht_l + go) = vl2;
    }
}

// ---------------------------------------------------------------------------
extern "C" void kernel_launch(void* const* d_in, const int* in_sizes, int n_in,
                              void* d_out, int out_size, void* d_ws, size_t ws_size,
                              hipStream_t stream) {
    (void)in_sizes; (void)n_in; (void)out_size; (void)ws_size;
    const float* x      = (const float*)d_in[0];
    const float* w_qkv  = (const float*)d_in[1];
    const float* w_proj = (const float*)d_in[2];
    const float* b_proj = (const float*)d_in[3];
    float* out = (float*)d_out;

    // workspace layout (bytes), total 50,331,648 (< 67 MB proven safe)
    char* ws = (char*)d_ws;
    ushort* xt_h = (ushort*)(ws);                       // 4,194,304
    ushort* xt_l = (ushort*)(ws + 4194304);             // 4,194,304
    ushort* wq_h = (ushort*)(ws + 8388608);             // 1,572,864
    ushort* wq_l = (ushort*)(ws + 9961472);             // 1,572,864
    ushort* wp_h = (ushort*)(ws + 11534336);            //   524,288
    ushort* wp_l = (ushort*)(ws + 12058624);            //   524,288
    ushort* qhT  = (ushort*)(ws + 12582912);            // 4,194,304
    ushort* qlT  = (ushort*)(ws + 16777216);            // 4,194,304
    ushort* khT  = (ushort*)(ws + 20971520);            // 4,194,304
    ushort* klT  = (ushort*)(ws + 25165824);            // 4,194,304
    ushort* vbT  = (ushort*)(ws + 29360128);            // 4,194,304
    ushort* ht_h = (ushort*)(ws + 33554432);            // 8,388,608
    ushort* ht_l = (ushort*)(ws + 41943040);            // 8,388,608

    split_w<<<1024, 256, 0, stream>>>(w_qkv, w_proj, wq_h, wq_l, wp_h, wp_l);
    for (int p = 0; p < 2; p++) {
        int bbase = p * 4;
        split_x<<<dim3(16, 8, 4), 256, 0, stream>>>(x, xt_h, xt_l, bbase);
        gemm_qkv<<<dim3(8, 12, 4), 256, 0, stream>>>(wq_h, wq_l, xt_h, xt_l,
                                                     qhT, qlT, khT, klT, vbT);
        attn_mfma<<<dim3(16, 32), 256, 0, stream>>>(qhT, qlT, khT, klT, vbT,
                                                    ht_h, ht_l, bbase);
    }
    gemm_proj<<<dim3(8, 4, 8), 256, 0, stream>>>(wp_h, wp_l, ht_h, ht_l, b_proj, out);
}

// Round 5
// 326.385 us; speedup vs baseline: 1.1052x; 1.1052x over previous
//
#include <hip/hip_runtime.h>
#include <math.h>

// ============================================================================
// Attention block (B=8, C=512, H=W=32, nh=8, hd=64) via bf16x3 MFMA.
// Round 5: attention reverted to the round-2 phase-barriered skeleton
// (measured 65 µs) — r3/r4's single-barrier + reg-prefetch structure both
// benched 107-108 µs with ALL pipes idle, so it's abandoned. Kept orthogonal
// wins: K staged from pre-split hi/lo planes (no u32 unpack), V single bf16
// plane (half staging bytes, PV = 1 MFMA), stride-68 LDS (conflict-free),
// wave-private P. GEMM cores unchanged from round 2.
// ============================================================================

typedef unsigned int u32;
typedef float  f32x4 __attribute__((ext_vector_type(4)));
typedef short  s16x8 __attribute__((ext_vector_type(8)));
typedef unsigned short u16x4 __attribute__((ext_vector_type(4)));
typedef unsigned int   u32x4 __attribute__((ext_vector_type(4)));

#define MFMA16(a, b, c) __builtin_amdgcn_mfma_f32_16x16x32_bf16(a, b, c, 0, 0, 0)

// split fp32 -> (hi bf16 << 16) | lo bf16.  hi = truncation, lo = RNE(f - hi)
__device__ __forceinline__ u32 splitpack(float f) {
    u32 b = __float_as_uint(f);
    u32 hb = b & 0xFFFF0000u;
    float lf = f - __uint_as_float(hb);
    u32 lb = __float_as_uint(lf);
    u32 lr = (lb + 0x7FFFu + ((lb >> 16) & 1u)) >> 16;
    return hb | (lr & 0xFFFFu);
}
__device__ __forceinline__ ushort f2bf(float f) {  // RNE fp32->bf16
    u32 b = __float_as_uint(f);
    return (ushort)((b + 0x7FFFu + ((b >> 16) & 1u)) >> 16);
}
__device__ __forceinline__ void unpack4(u32x4 v, u16x4& hi, u16x4& lo) {
    hi[0] = (ushort)(v.x >> 16); hi[1] = (ushort)(v.y >> 16);
    hi[2] = (ushort)(v.z >> 16); hi[3] = (ushort)(v.w >> 16);
    lo[0] = (ushort)v.x; lo[1] = (ushort)v.y;
    lo[2] = (ushort)v.z; lo[3] = (ushort)v.w;
}

// ---------------------------------------------------------------------------
// split_w: both weight matrices -> hi/lo bf16 planes, same [o][c] layout.
// ---------------------------------------------------------------------------
__global__ __launch_bounds__(256) void split_w(const float* __restrict__ wq,
                                               const float* __restrict__ wp,
                                               ushort* __restrict__ wq_h, ushort* __restrict__ wq_l,
                                               ushort* __restrict__ wp_h, ushort* __restrict__ wp_l) {
    size_t base = ((size_t)blockIdx.x * 256 + threadIdx.x) * 4;
    const float* src; ushort *dh, *dl; size_t off;
    if (base < 786432) { src = wq; dh = wq_h; dl = wq_l; off = base; }
    else               { src = wp; dh = wp_h; dl = wp_l; off = base - 786432; }
    f32x4 v = *(const f32x4*)(src + off);
    u16x4 hi, lo;
#pragma unroll
    for (int e = 0; e < 4; e++) { u32 pk = splitpack(v[e]); hi[e] = (ushort)(pk >> 16); lo[e] = (ushort)pk; }
    *(u16x4*)(dh + off) = hi;
    *(u16x4*)(dl + off) = lo;
}

// ---------------------------------------------------------------------------
// split_x: x[b][c][n] fp32 -> xt hi/lo [bl][n][c] bf16 (64x64 tile transpose).
// ---------------------------------------------------------------------------
__global__ __launch_bounds__(256) void split_x(const float* __restrict__ x,
                                               ushort* __restrict__ xh, ushort* __restrict__ xl,
                                               int bbase) {
    __shared__ __align__(16) ushort Th[64 * 72];
    __shared__ __align__(16) ushort Tl[64 * 72];
    const int t = threadIdx.x;
    const int n0 = blockIdx.x * 64, c0 = blockIdx.y * 64, bz = blockIdx.z;
    const int b = bbase + bz;
    const int c = t >> 2, nseg = (t & 3) * 4;
    const float* src = x + ((size_t)b * 512 + c0 + c) * 1024 + n0;
#pragma unroll
    for (int i = 0; i < 4; i++) {
        f32x4 v = *(const f32x4*)(src + nseg + i * 16);
#pragma unroll
        for (int e = 0; e < 4; e++) {
            u32 pk = splitpack(v[e]);
            int nl = nseg + i * 16 + e;
            Th[nl * 72 + c] = (ushort)(pk >> 16);
            Tl[nl * 72 + c] = (ushort)pk;
        }
    }
    __syncthreads();
#pragma unroll
    for (int i = 0; i < 2; i++) {
        int nl = i * 32 + (t >> 3);
        int u = t & 7;
        s16x8 vh = *(const s16x8*)(Th + nl * 72 + u * 8);
        s16x8 vl = *(const s16x8*)(Tl + nl * 72 + u * 8);
        size_t go = ((size_t)bz * 1024 + n0 + nl) * 512 + c0 + u * 8;
        *(s16x8*)(xh + go) = vh;
        *(s16x8*)(xl + go) = vl;
    }
}

// ---------------------------------------------------------------------------
// Shared bf16x3 GEMM mainloop: 128x128 tile, BK=32, reg-prefetched staging.
// acc[Mt][Nt]: D rows o = ohalf*64+Mt*16+quad*4+r, cols n = nhalf*64+Nt*16+l15.
// ---------------------------------------------------------------------------
__device__ __forceinline__ void gemm_core(
    const ushort* __restrict__ Ah_g, const ushort* __restrict__ Al_g, int arow0,
    const ushort* __restrict__ Bh_g, const ushort* __restrict__ Bl_g, size_t brow0,
    ushort* smem, f32x4 (&acc)[4][4]) {
    const int t = threadIdx.x;
    ushort* As_h = smem;
    ushort* As_l = smem + 5120;
    ushort* Bs_h = smem + 10240;
    ushort* Bs_l = smem + 15360;
    const int ro = t >> 1, cs = (t & 1) << 4;
    const size_t ga = (size_t)(arow0 + ro) * 512 + cs;
    const size_t gb = (brow0 + ro) * 512 + cs;
    const int l15 = t & 15, quad = (t >> 4) & 3, wv = t >> 6;
    const int lra = (((wv >> 1) * 64) + l15) * 40 + quad * 8;
    const int lrb = (((wv & 1) * 64) + l15) * 40 + quad * 8;
    const int lw = ro * 40 + cs;

    s16x8 vah0 = *(const s16x8*)(Ah_g + ga),     vah1 = *(const s16x8*)(Ah_g + ga + 8);
    s16x8 val0 = *(const s16x8*)(Al_g + ga),     val1 = *(const s16x8*)(Al_g + ga + 8);
    s16x8 vbh0 = *(const s16x8*)(Bh_g + gb),     vbh1 = *(const s16x8*)(Bh_g + gb + 8);
    s16x8 vbl0 = *(const s16x8*)(Bl_g + gb),     vbl1 = *(const s16x8*)(Bl_g + gb + 8);

    for (int k0 = 0; k0 < 512; k0 += 32) {
        __syncthreads();
        *(s16x8*)(As_h + lw) = vah0; *(s16x8*)(As_h + lw + 8) = vah1;
        *(s16x8*)(As_l + lw) = val0; *(s16x8*)(As_l + lw + 8) = val1;
        *(s16x8*)(Bs_h + lw) = vbh0; *(s16x8*)(Bs_h + lw + 8) = vbh1;
        *(s16x8*)(Bs_l + lw) = vbl0; *(s16x8*)(Bs_l + lw + 8) = vbl1;
        const int kn = (k0 + 32) & 511;  // wraps to 0 on last iter (discarded)
        vah0 = *(const s16x8*)(Ah_g + ga + kn); vah1 = *(const s16x8*)(Ah_g + ga + kn + 8);
        val0 = *(const s16x8*)(Al_g + ga + kn); val1 = *(const s16x8*)(Al_g + ga + kn + 8);
        vbh0 = *(const s16x8*)(Bh_g + gb + kn); vbh1 = *(const s16x8*)(Bh_g + gb + kn + 8);
        vbl0 = *(const s16x8*)(Bl_g + gb + kn); vbl1 = *(const s16x8*)(Bl_g + gb + kn + 8);
        __syncthreads();
        s16x8 ah[4], al[4], bh[4], bl[4];
#pragma unroll
        for (int Mt = 0; Mt < 4; Mt++) {
            ah[Mt] = *(const s16x8*)(As_h + lra + Mt * 640);
            al[Mt] = *(const s16x8*)(As_l + lra + Mt * 640);
        }
#pragma unroll
        for (int Nt = 0; Nt < 4; Nt++) {
            bh[Nt] = *(const s16x8*)(Bs_h + lrb + Nt * 640);
            bl[Nt] = *(const s16x8*)(Bs_l + lrb + Nt * 640);
        }
#pragma unroll
        for (int Mt = 0; Mt < 4; Mt++)
#pragma unroll
            for (int Nt = 0; Nt < 4; Nt++) {
                acc[Mt][Nt] = MFMA16(ah[Mt], bh[Nt], acc[Mt][Nt]);
                acc[Mt][Nt] = MFMA16(ah[Mt], bl[Nt], acc[Mt][Nt]);
                acc[Mt][Nt] = MFMA16(al[Mt], bh[Nt], acc[Mt][Nt]);
            }
    }
    __syncthreads();  // LDS free for epilogue reuse
}

// ---------------------------------------------------------------------------
// QKV GEMM. o-halves (64 rows) align exactly to q/k/v roles: g = ot*2+ohalf,
// role = g%3 (0=q,1=k,2=v), head = g/3.  Q/K -> LDS transpose -> hi/lo bf16
// planes [b][h][n][d]; V -> single bf16 plane [b][h][d][n].
// ---------------------------------------------------------------------------
__global__ __launch_bounds__(256) void gemm_qkv(
    const ushort* __restrict__ wq_h, const ushort* __restrict__ wq_l,
    const ushort* __restrict__ xt_h, const ushort* __restrict__ xt_l,
    ushort* __restrict__ qhT, ushort* __restrict__ qlT,
    ushort* __restrict__ khT, ushort* __restrict__ klT,
    ushort* __restrict__ vbT) {
    __shared__ __align__(16) ushort smem[20480];
    f32x4 acc[4][4];
#pragma unroll
    for (int i = 0; i < 4; i++)
#pragma unroll
        for (int j = 0; j < 4; j++) acc[i][j] = (f32x4)0.0f;

    const int n0 = blockIdx.x * 128, o0 = blockIdx.y * 128, bz = blockIdx.z;
    gemm_core(wq_h, wq_l, o0, xt_h, xt_l, (size_t)bz * 1024 + n0, smem, acc);

    const int t = threadIdx.x;
    const int l15 = t & 15, quad = (t >> 4) & 3, wv = t >> 6, lane = t & 63;
    const int g = blockIdx.y * 2 + (wv >> 1);
    const int role = g % 3, head = g / 3;
    const int nh = (wv & 1) * 64;
    const size_t hb = (size_t)bz * 8 + head;
    const float scale = (role == 0) ? 0.125f : 1.0f;

    if (role < 2) {
        ushort* dh = (role == 0) ? qhT : khT;
        ushort* dl = (role == 0) ? qlT : klT;
        u32* T = (u32*)smem + wv * 2304;             // per-wave [64 n][36] u32
        const size_t rowbase = hb * 1024 + n0 + nh;  // pixel row index
#pragma unroll
        for (int sp = 0; sp < 2; sp++) {
#pragma unroll
            for (int Mti = 0; Mti < 2; Mti++)
#pragma unroll
                for (int Nt = 0; Nt < 4; Nt++) {
                    f32x4 v = acc[sp * 2 + Mti][Nt];
                    u32x4 pix;
#pragma unroll
                    for (int r = 0; r < 4; r++) pix[r] = splitpack(v[r] * scale);
                    *(u32x4*)(T + (Nt * 16 + l15) * 36 + Mti * 16 + quad * 4) = pix;
                }
            asm volatile("s_waitcnt lgkmcnt(0)" ::: "memory");
#pragma unroll
            for (int i = 0; i < 8; i++) {
                int nl = i * 8 + (lane >> 3);
                u32x4 vv = *(const u32x4*)(T + nl * 36 + (lane & 7) * 4);
                u16x4 hi, lo; unpack4(vv, hi, lo);
                size_t go = (rowbase + nl) * 64 + sp * 32 + (lane & 7) * 4;
                *(u16x4*)(dh + go) = hi;
                *(u16x4*)(dl + go) = lo;
            }
            asm volatile("s_waitcnt lgkmcnt(0)" ::: "memory");
        }
    } else {
        const size_t vb2 = hb * 64 * 1024 + (size_t)(n0 + nh);
#pragma unroll
        for (int Mt = 0; Mt < 4; Mt++)
#pragma unroll
            for (int Nt = 0; Nt < 4; Nt++)
#pragma unroll
                for (int r = 0; r < 4; r++)
                    vbT[vb2 + (size_t)(Mt * 16 + quad * 4 + r) * 1024 + Nt * 16 + l15] =
                        f2bf(acc[Mt][Nt][r]);
    }
}

// ---------------------------------------------------------------------------
// Proj GEMM: out fp32 + bias, direct C/D stores.
// ---------------------------------------------------------------------------
__global__ __launch_bounds__(256) void gemm_proj(
    const ushort* __restrict__ wp_h, const ushort* __restrict__ wp_l,
    const ushort* __restrict__ ht_h, const ushort* __restrict__ ht_l,
    const float* __restrict__ bias, float* __restrict__ out) {
    __shared__ __align__(16) ushort smem[20480];
    f32x4 acc[4][4];
#pragma unroll
    for (int i = 0; i < 4; i++)
#pragma unroll
        for (int j = 0; j < 4; j++) acc[i][j] = (f32x4)0.0f;

    const int n0 = blockIdx.x * 128, o0 = blockIdx.y * 128, bz = blockIdx.z;
    gemm_core(wp_h, wp_l, o0, ht_h, ht_l, (size_t)bz * 1024 + n0, smem, acc);

    const int t = threadIdx.x;
    const int l15 = t & 15, quad = (t >> 4) & 3, wv = t >> 6;
#pragma unroll
    for (int Mt = 0; Mt < 4; Mt++)
#pragma unroll
        for (int Nt = 0; Nt < 4; Nt++) {
            int ob = o0 + (wv >> 1) * 64 + Mt * 16 + quad * 4;
            int nn = n0 + (wv & 1) * 64 + Nt * 16 + l15;
#pragma unroll
            for (int r = 0; r < 4; r++)
                out[((size_t)bz * 512 + ob + r) * 1024 + nn] = acc[Mt][Nt][r] + bias[ob + r];
        }
}

// ---------------------------------------------------------------------------
// Flash attention, round 5 (= round-2 skeleton + layout wins).  256 threads
// (4 waves), one (b,h) + 128 queries per block, grid (8,32)=256 blocks.
// Per key-tile iter: stage K hi/lo -> barrier -> S(3-MFMA)+softmax+P(wave-
// private) -> barrier -> stage V (single bf16, reuses Kh plane) -> barrier
// -> PV(1 MFMA).  Strides 68 ushort (2-way bank aliasing = free).
// LDS (ushort): Kh[64][68]@0, Kl[64][68]@4352, Ps[128][68]@8704; epilogue
// reuses as OLh[128][72]@0 / OLl@9216.  Total 18432 ushort = 36,864 B.
// ---------------------------------------------------------------------------
__global__ __launch_bounds__(256, 2) void attn_mfma(
    const ushort* __restrict__ qhT, const ushort* __restrict__ qlT,
    const ushort* __restrict__ khT, const ushort* __restrict__ klT,
    const ushort* __restrict__ vbT,
    ushort* __restrict__ ht_h, ushort* __restrict__ ht_l, int bbase) {
    __shared__ __align__(16) ushort sm[18432];
    ushort* Kh = sm;           // [64][68]  (also V plane in phase C)
    ushort* Kl = sm + 4352;    // [64][68]
    ushort* Ps = sm + 8704;    // [128][68] wave-private rows
    const int t = threadIdx.x;
    const int qt = blockIdx.x, bh = blockIdx.y;
    const int bl = bh >> 3, h = bh & 7;
    const int m0 = qt * 128;
    const size_t hb = (size_t)bl * 8 + h;
    const int l15 = t & 15, quad = (t >> 4) & 3, wv = t >> 6;
    const int srow = t >> 2, scol = (t & 3) * 16;   // staging: 64 rows x 4 chunks

    // Persistent Q fragments (pre-scaled by 0.125); wave owns m-tiles wv*2+Nt
    s16x8 qfh[2][2], qfl[2][2];  // [Nt][ks]
#pragma unroll
    for (int Nt = 0; Nt < 2; Nt++) {
        const size_t qb = (hb * 1024 + m0 + (wv * 2 + Nt) * 16 + l15) * 64 + quad * 8;
        qfh[Nt][0] = *(const s16x8*)(qhT + qb);
        qfh[Nt][1] = *(const s16x8*)(qhT + qb + 32);
        qfl[Nt][0] = *(const s16x8*)(qlT + qb);
        qfl[Nt][1] = *(const s16x8*)(qlT + qb + 32);
    }

    f32x4 O[4][2];
#pragma unroll
    for (int i = 0; i < 4; i++) { O[i][0] = (f32x4)0.0f; O[i][1] = (f32x4)0.0f; }
    float mrun[2] = {-3.0e38f, -3.0e38f}, lrun[2] = {0.f, 0.f};

    const ushort* khb = khT + hb * 1024 * 64;
    const ushort* klb = klT + hb * 1024 * 64;
    const ushort* vbb = vbT + hb * 64 * 1024;

    for (int kt = 0; kt < 16; kt++) {
        __syncthreads();  // prev PV done reading V (Kh plane) and Ps
        {   // Phase A: stage K tile [64 nk][64 d] hi+lo
            const size_t gk = (size_t)(kt * 64 + srow) * 64 + scol;
            s16x8 h0 = *(const s16x8*)(khb + gk);
            s16x8 h1 = *(const s16x8*)(khb + gk + 8);
            s16x8 l0 = *(const s16x8*)(klb + gk);
            s16x8 l1 = *(const s16x8*)(klb + gk + 8);
            *(s16x8*)(Kh + srow * 68 + scol) = h0;
            *(s16x8*)(Kh + srow * 68 + scol + 8) = h1;
            *(s16x8*)(Kl + srow * 68 + scol) = l0;
            *(s16x8*)(Kl + srow * 68 + scol + 8) = l1;
        }
        __syncthreads();
        // Phase B: S = K^T Q (3-MFMA), online softmax, P -> wave-private LDS
        f32x4 S[4][2];
#pragma unroll
        for (int i = 0; i < 4; i++) { S[i][0] = (f32x4)0.0f; S[i][1] = (f32x4)0.0f; }
#pragma unroll
        for (int ks = 0; ks < 2; ks++) {
            s16x8 kh[4], kl[4];
#pragma unroll
            for (int Mt = 0; Mt < 4; Mt++) {
                kh[Mt] = *(const s16x8*)(Kh + (Mt * 16 + l15) * 68 + ks * 32 + quad * 8);
                kl[Mt] = *(const s16x8*)(Kl + (Mt * 16 + l15) * 68 + ks * 32 + quad * 8);
            }
#pragma unroll
            for (int Mt = 0; Mt < 4; Mt++)
#pragma unroll
                for (int Nt = 0; Nt < 2; Nt++) {
                    S[Mt][Nt] = MFMA16(kh[Mt], qfh[Nt][ks], S[Mt][Nt]);
                    S[Mt][Nt] = MFMA16(kh[Mt], qfl[Nt][ks], S[Mt][Nt]);
                    S[Mt][Nt] = MFMA16(kl[Mt], qfh[Nt][ks], S[Mt][Nt]);
                }
        }
        float alpha[2];
#pragma unroll
        for (int Nt = 0; Nt < 2; Nt++) {
            float tm = -3.0e38f;
#pragma unroll
            for (int Mt = 0; Mt < 4; Mt++)
#pragma unroll
                for (int r = 0; r < 4; r++) tm = fmaxf(tm, S[Mt][Nt][r]);
            tm = fmaxf(tm, __shfl_xor(tm, 16));
            tm = fmaxf(tm, __shfl_xor(tm, 32));
            const float mnew = fmaxf(mrun[Nt], tm);
            alpha[Nt] = __expf(mrun[Nt] - mnew);
            float ts = 0.f;
#pragma unroll
            for (int Mt = 0; Mt < 4; Mt++)
#pragma unroll
                for (int r = 0; r < 4; r++) {
                    float p = __expf(S[Mt][Nt][r] - mnew);
                    S[Mt][Nt][r] = p;
                    ts += p;
                }
            ts += __shfl_xor(ts, 16);
            ts += __shfl_xor(ts, 32);
            lrun[Nt] = lrun[Nt] * alpha[Nt] + ts;
            mrun[Nt] = mnew;
        }
#pragma unroll
        for (int Mt = 0; Mt < 4; Mt++)
#pragma unroll
            for (int Nt = 0; Nt < 2; Nt++) {
                u16x4 pb;
#pragma unroll
                for (int r = 0; r < 4; r++) pb[r] = f2bf(S[Mt][Nt][r]);
                *(u16x4*)(Ps + ((wv * 2 + Nt) * 16 + l15) * 68 + Mt * 16 + quad * 4) = pb;
            }
        __syncthreads();  // all waves done reading K fragments
        {   // Phase C: stage V tile [64 d][64 nk] (single bf16) over Kh plane
            const size_t gv = (size_t)srow * 1024 + kt * 64 + scol;
            s16x8 v0 = *(const s16x8*)(vbb + gv);
            s16x8 v1 = *(const s16x8*)(vbb + gv + 8);
            *(s16x8*)(Kh + srow * 68 + scol) = v0;
            *(s16x8*)(Kh + srow * 68 + scol + 8) = v1;
        }
        __syncthreads();
        // Phase D: O = O*alpha + V @ P
#pragma unroll
        for (int Mt = 0; Mt < 4; Mt++)
#pragma unroll
            for (int Nt = 0; Nt < 2; Nt++) O[Mt][Nt] *= alpha[Nt];
#pragma unroll
        for (int ks = 0; ks < 2; ks++) {
            s16x8 vf[4], pf[2];
#pragma unroll
            for (int Mt = 0; Mt < 4; Mt++)
                vf[Mt] = *(const s16x8*)(Kh + (Mt * 16 + l15) * 68 + ks * 32 + quad * 8);
#pragma unroll
            for (int Nt = 0; Nt < 2; Nt++)
                pf[Nt] = *(const s16x8*)(Ps + ((wv * 2 + Nt) * 16 + l15) * 68 + ks * 32 + quad * 8);
#pragma unroll
            for (int Mt = 0; Mt < 4; Mt++)
#pragma unroll
                for (int Nt = 0; Nt < 2; Nt++)
                    O[Mt][Nt] = MFMA16(vf[Mt], pf[Nt], O[Mt][Nt]);
        }
    }

    // Epilogue: O /= l, split hi/lo, LDS gather -> coalesced hT stores
    __syncthreads();  // all waves done with Kh/Ps before overwrite
    ushort* OLh = sm;          // [128][72]
    ushort* OLl = sm + 9216;
    float linv[2] = {1.f / lrun[0], 1.f / lrun[1]};
#pragma unroll
    for (int Mt = 0; Mt < 4; Mt++)
#pragma unroll
        for (int Nt = 0; Nt < 2; Nt++) {
            u16x4 hi, lo;
#pragma unroll
            for (int r = 0; r < 4; r++) {
                u32 pk = splitpack(O[Mt][Nt][r] * linv[Nt]);
                hi[r] = (ushort)(pk >> 16);
                lo[r] = (ushort)pk;
            }
            const int m = (wv * 2 + Nt) * 16 + l15;
            *(u16x4*)(OLh + m * 72 + Mt * 16 + quad * 4) = hi;
            *(u16x4*)(OLl + m * 72 + Mt * 16 + quad * 4) = lo;
        }
    __syncthreads();
    const size_t ob = (size_t)(bbase + bl) * 1024 + m0;
#pragma unroll
    for (int i = 0; i < 4; i++) {
        const int m = i * 32 + (t >> 3);
        const int u = t & 7;
        s16x8 vh2 = *(const s16x8*)(OLh + m * 72 + u * 8);
        s16x8 vl2 = *(const s16x8*)(OLl + m * 72 + u * 8);
        size_t go = (ob + m) * 512 + h * 64 + u * 8;
        *(s16x8*)(ht_h + go) = vh2;
        *(s16x8*)(ht_l + go) = vl2;
    }
}

// ---------------------------------------------------------------------------
extern "C" void kernel_launch(void* const* d_in, const int* in_sizes, int n_in,
                              void* d_out, int out_size, void* d_ws, size_t ws_size,
                              hipStream_t stream) {
    (void)in_sizes; (void)n_in; (void)out_size; (void)ws_size;
    const float* x      = (const float*)d_in[0];
    const float* w_qkv  = (const float*)d_in[1];
    const float* w_proj = (const float*)d_in[2];
    const float* b_proj = (const float*)d_in[3];
    float* out = (float*)d_out;

    // workspace layout (bytes), total 50,331,648 (< 67 MB proven safe)
    char* ws = (char*)d_ws;
    ushort* xt_h = (ushort*)(ws);                       // 4,194,304
    ushort* xt_l = (ushort*)(ws + 4194304);             // 4,194,304
    ushort* wq_h = (ushort*)(ws + 8388608);             // 1,572,864
    ushort* wq_l = (ushort*)(ws + 9961472);             // 1,572,864
    ushort* wp_h = (ushort*)(ws + 11534336);            //   524,288
    ushort* wp_l = (ushort*)(ws + 12058624);            //   524,288
    ushort* qhT  = (ushort*)(ws + 12582912);            // 4,194,304
    ushort* qlT  = (ushort*)(ws + 16777216);            // 4,194,304
    ushort* khT  = (ushort*)(ws + 20971520);            // 4,194,304
    ushort* klT  = (ushort*)(ws + 25165824);            // 4,194,304
    ushort* vbT  = (ushort*)(ws + 29360128);            // 4,194,304
    ushort* ht_h = (ushort*)(ws + 33554432);            // 8,388,608
    ushort* ht_l = (ushort*)(ws + 41943040);            // 8,388,608

    split_w<<<1024, 256, 0, stream>>>(w_qkv, w_proj, wq_h, wq_l, wp_h, wp_l);
    for (int p = 0; p < 2; p++) {
        int bbase = p * 4;
        split_x<<<dim3(16, 8, 4), 256, 0, stream>>>(x, xt_h, xt_l, bbase);
        gemm_qkv<<<dim3(8, 12, 4), 256, 0, stream>>>(wq_h, wq_l, xt_h, xt_l,
                                                     qhT, qlT, khT, klT, vbT);
        attn_mfma<<<dim3(8, 32), 256, 0, stream>>>(qhT, qlT, khT, klT, vbT,
                                                   ht_h, ht_l, bbase);
    }
    gemm_proj<<<dim3(8, 4, 8), 256, 0, stream>>>(wp_h, wp_l, ht_h, ht_l, b_proj, out);
}

// Round 6
// 232.694 us; speedup vs baseline: 1.5502x; 1.4026x over previous
//
#include <hip/hip_runtime.h>
#include <math.h>

// ============================================================================
// Attention block (B=8, C=512, H=W=32, nh=8, hd=64) via bf16x3 MFMA.
// Round 6: BARRIER-FREE attention K-loop. K ([n][d]) and V ([d][n]) layouts
// make MFMA A-fragments directly global-loadable per lane (16B), so no LDS
// staging and no __syncthreads in the hot loop; waves run independently and
// hide each other's L2 latency. P stays in wave-private LDS (lgkmcnt only).
// Single pass over all 8 batches (ht aliases xt; ws 60 MB): attn grid 512 =
// 2 blocks/CU via __launch_bounds__(256,2). GEMM cores unchanged.
// r3/r4 lesson: barrier+manual-prefetch structures serialize; r5 lesson: any
// 4-wave/CU barrier-phased loop is ~90% stall regardless of per-iter work.
// ============================================================================

typedef unsigned int u32;
typedef float  f32x4 __attribute__((ext_vector_type(4)));
typedef short  s16x8 __attribute__((ext_vector_type(8)));
typedef unsigned short u16x4 __attribute__((ext_vector_type(4)));
typedef unsigned int   u32x4 __attribute__((ext_vector_type(4)));

#define MFMA16(a, b, c) __builtin_amdgcn_mfma_f32_16x16x32_bf16(a, b, c, 0, 0, 0)

// split fp32 -> (hi bf16 << 16) | lo bf16.  hi = truncation, lo = RNE(f - hi)
__device__ __forceinline__ u32 splitpack(float f) {
    u32 b = __float_as_uint(f);
    u32 hb = b & 0xFFFF0000u;
    float lf = f - __uint_as_float(hb);
    u32 lb = __float_as_uint(lf);
    u32 lr = (lb + 0x7FFFu + ((lb >> 16) & 1u)) >> 16;
    return hb | (lr & 0xFFFFu);
}
__device__ __forceinline__ ushort f2bf(float f) {  // RNE fp32->bf16
    u32 b = __float_as_uint(f);
    return (ushort)((b + 0x7FFFu + ((b >> 16) & 1u)) >> 16);
}
__device__ __forceinline__ void unpack4(u32x4 v, u16x4& hi, u16x4& lo) {
    hi[0] = (ushort)(v.x >> 16); hi[1] = (ushort)(v.y >> 16);
    hi[2] = (ushort)(v.z >> 16); hi[3] = (ushort)(v.w >> 16);
    lo[0] = (ushort)v.x; lo[1] = (ushort)v.y;
    lo[2] = (ushort)v.z; lo[3] = (ushort)v.w;
}

// ---------------------------------------------------------------------------
// split_w: both weight matrices -> hi/lo bf16 planes, same [o][c] layout.
// ---------------------------------------------------------------------------
__global__ __launch_bounds__(256) void split_w(const float* __restrict__ wq,
                                               const float* __restrict__ wp,
                                               ushort* __restrict__ wq_h, ushort* __restrict__ wq_l,
                                               ushort* __restrict__ wp_h, ushort* __restrict__ wp_l) {
    size_t base = ((size_t)blockIdx.x * 256 + threadIdx.x) * 4;
    const float* src; ushort *dh, *dl; size_t off;
    if (base < 786432) { src = wq; dh = wq_h; dl = wq_l; off = base; }
    else               { src = wp; dh = wp_h; dl = wp_l; off = base - 786432; }
    f32x4 v = *(const f32x4*)(src + off);
    u16x4 hi, lo;
#pragma unroll
    for (int e = 0; e < 4; e++) { u32 pk = splitpack(v[e]); hi[e] = (ushort)(pk >> 16); lo[e] = (ushort)pk; }
    *(u16x4*)(dh + off) = hi;
    *(u16x4*)(dl + off) = lo;
}

// ---------------------------------------------------------------------------
// split_x: x[b][c][n] fp32 -> xt hi/lo [b][n][c] bf16 (64x64 tile transpose).
// ---------------------------------------------------------------------------
__global__ __launch_bounds__(256) void split_x(const float* __restrict__ x,
                                               ushort* __restrict__ xh, ushort* __restrict__ xl) {
    __shared__ __align__(16) ushort Th[64 * 72];
    __shared__ __align__(16) ushort Tl[64 * 72];
    const int t = threadIdx.x;
    const int n0 = blockIdx.x * 64, c0 = blockIdx.y * 64, b = blockIdx.z;
    const int c = t >> 2, nseg = (t & 3) * 4;
    const float* src = x + ((size_t)b * 512 + c0 + c) * 1024 + n0;
#pragma unroll
    for (int i = 0; i < 4; i++) {
        f32x4 v = *(const f32x4*)(src + nseg + i * 16);
#pragma unroll
        for (int e = 0; e < 4; e++) {
            u32 pk = splitpack(v[e]);
            int nl = nseg + i * 16 + e;
            Th[nl * 72 + c] = (ushort)(pk >> 16);
            Tl[nl * 72 + c] = (ushort)pk;
        }
    }
    __syncthreads();
#pragma unroll
    for (int i = 0; i < 2; i++) {
        int nl = i * 32 + (t >> 3);
        int u = t & 7;
        s16x8 vh = *(const s16x8*)(Th + nl * 72 + u * 8);
        s16x8 vl = *(const s16x8*)(Tl + nl * 72 + u * 8);
        size_t go = ((size_t)b * 1024 + n0 + nl) * 512 + c0 + u * 8;
        *(s16x8*)(xh + go) = vh;
        *(s16x8*)(xl + go) = vl;
    }
}

// ---------------------------------------------------------------------------
// Shared bf16x3 GEMM mainloop: 128x128 tile, BK=32, reg-prefetched staging.
// acc[Mt][Nt]: D rows o = ohalf*64+Mt*16+quad*4+r, cols n = nhalf*64+Nt*16+l15.
// ---------------------------------------------------------------------------
__device__ __forceinline__ void gemm_core(
    const ushort* __restrict__ Ah_g, const ushort* __restrict__ Al_g, int arow0,
    const ushort* __restrict__ Bh_g, const ushort* __restrict__ Bl_g, size_t brow0,
    ushort* smem, f32x4 (&acc)[4][4]) {
    const int t = threadIdx.x;
    ushort* As_h = smem;
    ushort* As_l = smem + 5120;
    ushort* Bs_h = smem + 10240;
    ushort* Bs_l = smem + 15360;
    const int ro = t >> 1, cs = (t & 1) << 4;
    const size_t ga = (size_t)(arow0 + ro) * 512 + cs;
    const size_t gb = (brow0 + ro) * 512 + cs;
    const int l15 = t & 15, quad = (t >> 4) & 3, wv = t >> 6;
    const int lra = (((wv >> 1) * 64) + l15) * 40 + quad * 8;
    const int lrb = (((wv & 1) * 64) + l15) * 40 + quad * 8;
    const int lw = ro * 40 + cs;

    s16x8 vah0 = *(const s16x8*)(Ah_g + ga),     vah1 = *(const s16x8*)(Ah_g + ga + 8);
    s16x8 val0 = *(const s16x8*)(Al_g + ga),     val1 = *(const s16x8*)(Al_g + ga + 8);
    s16x8 vbh0 = *(const s16x8*)(Bh_g + gb),     vbh1 = *(const s16x8*)(Bh_g + gb + 8);
    s16x8 vbl0 = *(const s16x8*)(Bl_g + gb),     vbl1 = *(const s16x8*)(Bl_g + gb + 8);

    for (int k0 = 0; k0 < 512; k0 += 32) {
        __syncthreads();
        *(s16x8*)(As_h + lw) = vah0; *(s16x8*)(As_h + lw + 8) = vah1;
        *(s16x8*)(As_l + lw) = val0; *(s16x8*)(As_l + lw + 8) = val1;
        *(s16x8*)(Bs_h + lw) = vbh0; *(s16x8*)(Bs_h + lw + 8) = vbh1;
        *(s16x8*)(Bs_l + lw) = vbl0; *(s16x8*)(Bs_l + lw + 8) = vbl1;
        const int kn = (k0 + 32) & 511;  // wraps to 0 on last iter (discarded)
        vah0 = *(const s16x8*)(Ah_g + ga + kn); vah1 = *(const s16x8*)(Ah_g + ga + kn + 8);
        val0 = *(const s16x8*)(Al_g + ga + kn); val1 = *(const s16x8*)(Al_g + ga + kn + 8);
        vbh0 = *(const s16x8*)(Bh_g + gb + kn); vbh1 = *(const s16x8*)(Bh_g + gb + kn + 8);
        vbl0 = *(const s16x8*)(Bl_g + gb + kn); vbl1 = *(const s16x8*)(Bl_g + gb + kn + 8);
        __syncthreads();
        s16x8 ah[4], al[4], bh[4], bl[4];
#pragma unroll
        for (int Mt = 0; Mt < 4; Mt++) {
            ah[Mt] = *(const s16x8*)(As_h + lra + Mt * 640);
            al[Mt] = *(const s16x8*)(As_l + lra + Mt * 640);
        }
#pragma unroll
        for (int Nt = 0; Nt < 4; Nt++) {
            bh[Nt] = *(const s16x8*)(Bs_h + lrb + Nt * 640);
            bl[Nt] = *(const s16x8*)(Bs_l + lrb + Nt * 640);
        }
#pragma unroll
        for (int Mt = 0; Mt < 4; Mt++)
#pragma unroll
            for (int Nt = 0; Nt < 4; Nt++) {
                acc[Mt][Nt] = MFMA16(ah[Mt], bh[Nt], acc[Mt][Nt]);
                acc[Mt][Nt] = MFMA16(ah[Mt], bl[Nt], acc[Mt][Nt]);
                acc[Mt][Nt] = MFMA16(al[Mt], bh[Nt], acc[Mt][Nt]);
            }
    }
    __syncthreads();  // LDS free for epilogue reuse
}

// ---------------------------------------------------------------------------
// QKV GEMM. o-halves (64 rows) align exactly to q/k/v roles: g = ot*2+ohalf,
// role = g%3 (0=q,1=k,2=v), head = g/3.  Q/K -> LDS transpose -> hi/lo bf16
// planes [b][h][n][d]; V -> single bf16 plane [b][h][d][n].
// ---------------------------------------------------------------------------
__global__ __launch_bounds__(256) void gemm_qkv(
    const ushort* __restrict__ wq_h, const ushort* __restrict__ wq_l,
    const ushort* __restrict__ xt_h, const ushort* __restrict__ xt_l,
    ushort* __restrict__ qhT, ushort* __restrict__ qlT,
    ushort* __restrict__ khT, ushort* __restrict__ klT,
    ushort* __restrict__ vbT) {
    __shared__ __align__(16) ushort smem[20480];
    f32x4 acc[4][4];
#pragma unroll
    for (int i = 0; i < 4; i++)
#pragma unroll
        for (int j = 0; j < 4; j++) acc[i][j] = (f32x4)0.0f;

    const int n0 = blockIdx.x * 128, o0 = blockIdx.y * 128, bz = blockIdx.z;
    gemm_core(wq_h, wq_l, o0, xt_h, xt_l, (size_t)bz * 1024 + n0, smem, acc);

    const int t = threadIdx.x;
    const int l15 = t & 15, quad = (t >> 4) & 3, wv = t >> 6, lane = t & 63;
    const int g = blockIdx.y * 2 + (wv >> 1);
    const int role = g % 3, head = g / 3;
    const int nh = (wv & 1) * 64;
    const size_t hb = (size_t)bz * 8 + head;
    const float scale = (role == 0) ? 0.125f : 1.0f;

    if (role < 2) {
        ushort* dh = (role == 0) ? qhT : khT;
        ushort* dl = (role == 0) ? qlT : klT;
        u32* T = (u32*)smem + wv * 2304;             // per-wave [64 n][36] u32
        const size_t rowbase = hb * 1024 + n0 + nh;  // pixel row index
#pragma unroll
        for (int sp = 0; sp < 2; sp++) {
#pragma unroll
            for (int Mti = 0; Mti < 2; Mti++)
#pragma unroll
                for (int Nt = 0; Nt < 4; Nt++) {
                    f32x4 v = acc[sp * 2 + Mti][Nt];
                    u32x4 pix;
#pragma unroll
                    for (int r = 0; r < 4; r++) pix[r] = splitpack(v[r] * scale);
                    *(u32x4*)(T + (Nt * 16 + l15) * 36 + Mti * 16 + quad * 4) = pix;
                }
            asm volatile("s_waitcnt lgkmcnt(0)" ::: "memory");
#pragma unroll
            for (int i = 0; i < 8; i++) {
                int nl = i * 8 + (lane >> 3);
                u32x4 vv = *(const u32x4*)(T + nl * 36 + (lane & 7) * 4);
                u16x4 hi, lo; unpack4(vv, hi, lo);
                size_t go = (rowbase + nl) * 64 + sp * 32 + (lane & 7) * 4;
                *(u16x4*)(dh + go) = hi;
                *(u16x4*)(dl + go) = lo;
            }
            asm volatile("s_waitcnt lgkmcnt(0)" ::: "memory");
        }
    } else {
        const size_t vb2 = hb * 64 * 1024 + (size_t)(n0 + nh);
#pragma unroll
        for (int Mt = 0; Mt < 4; Mt++)
#pragma unroll
            for (int Nt = 0; Nt < 4; Nt++)
#pragma unroll
                for (int r = 0; r < 4; r++)
                    vbT[vb2 + (size_t)(Mt * 16 + quad * 4 + r) * 1024 + Nt * 16 + l15] =
                        f2bf(acc[Mt][Nt][r]);
    }
}

// ---------------------------------------------------------------------------
// Proj GEMM: out fp32 + bias, direct C/D stores.
// ---------------------------------------------------------------------------
__global__ __launch_bounds__(256) void gemm_proj(
    const ushort* __restrict__ wp_h, const ushort* __restrict__ wp_l,
    const ushort* __restrict__ ht_h, const ushort* __restrict__ ht_l,
    const float* __restrict__ bias, float* __restrict__ out) {
    __shared__ __align__(16) ushort smem[20480];
    f32x4 acc[4][4];
#pragma unroll
    for (int i = 0; i < 4; i++)
#pragma unroll
        for (int j = 0; j < 4; j++) acc[i][j] = (f32x4)0.0f;

    const int n0 = blockIdx.x * 128, o0 = blockIdx.y * 128, bz = blockIdx.z;
    gemm_core(wp_h, wp_l, o0, ht_h, ht_l, (size_t)bz * 1024 + n0, smem, acc);

    const int t = threadIdx.x;
    const int l15 = t & 15, quad = (t >> 4) & 3, wv = t >> 6;
#pragma unroll
    for (int Mt = 0; Mt < 4; Mt++)
#pragma unroll
        for (int Nt = 0; Nt < 4; Nt++) {
            int ob = o0 + (wv >> 1) * 64 + Mt * 16 + quad * 4;
            int nn = n0 + (wv & 1) * 64 + Nt * 16 + l15;
#pragma unroll
            for (int r = 0; r < 4; r++)
                out[((size_t)bz * 512 + ob + r) * 1024 + nn] = acc[Mt][Nt][r] + bias[ob + r];
        }
}

// ---------------------------------------------------------------------------
// Flash attention, round 6: barrier-free K-loop.  256 threads (4 waves), one
// (b,h) + 128 queries per block, grid (8,64)=512 blocks = 2 blocks/CU.
// Per iter: 16 K-frag + 8 V-frag global loads straight into MFMA operand
// registers (K first so S waits only vmcnt for K; V latency hides under
// softmax), S 3-MFMA, shuffle softmax, P via wave-private LDS, PV 1-MFMA.
// NO __syncthreads until the epilogue.  LDS: Ps[128][68]@0, OLh[128][72]@8704,
// OLl[128][72]@17920 -> 54,272 B (2 blocks/CU = 108.5 KB < 160 KB).
// ---------------------------------------------------------------------------
__global__ __launch_bounds__(256, 2) void attn_mfma(
    const ushort* __restrict__ qhT, const ushort* __restrict__ qlT,
    const ushort* __restrict__ khT, const ushort* __restrict__ klT,
    const ushort* __restrict__ vbT,
    ushort* __restrict__ ht_h, ushort* __restrict__ ht_l) {
    __shared__ __align__(16) ushort sm[27136];
    ushort* Ps  = sm;            // [128][68] wave-private rows
    ushort* OLh = sm + 8704;     // [128][72]
    ushort* OLl = sm + 17920;    // [128][72]
    const int t = threadIdx.x;
    const int qt = blockIdx.x, bh = blockIdx.y;
    const int b = bh >> 3, h = bh & 7;
    const int m0 = qt * 128;
    const size_t hb = (size_t)bh;
    const int l15 = t & 15, quad = (t >> 4) & 3, wv = t >> 6;

    // Persistent Q fragments (pre-scaled by 0.125); wave owns m-tiles wv*2+Nt
    s16x8 qfh[2][2], qfl[2][2];  // [Nt][ks]
#pragma unroll
    for (int Nt = 0; Nt < 2; Nt++) {
        const size_t qb = (hb * 1024 + m0 + (wv * 2 + Nt) * 16 + l15) * 64 + quad * 8;
        qfh[Nt][0] = *(const s16x8*)(qhT + qb);
        qfh[Nt][1] = *(const s16x8*)(qhT + qb + 32);
        qfl[Nt][0] = *(const s16x8*)(qlT + qb);
        qfl[Nt][1] = *(const s16x8*)(qlT + qb + 32);
    }

    f32x4 O[4][2];
#pragma unroll
    for (int i = 0; i < 4; i++) { O[i][0] = (f32x4)0.0f; O[i][1] = (f32x4)0.0f; }
    float mrun[2] = {-3.0e38f, -3.0e38f}, lrun[2] = {0.f, 0.f};

    const ushort* khb = khT + hb * 65536;
    const ushort* klb = klT + hb * 65536;
    const ushort* vbb = vbT + hb * 65536;
    const int pr = (wv * 2) * 16 + l15;  // wave's Ps row base (Nt adds 16)

#pragma unroll 2
    for (int kt = 0; kt < 16; kt++) {
        // K frags first (S depends on them), V after (hidden under softmax)
        s16x8 kh[2][4], kl[2][4], vf[2][4];
        const size_t kbase = (size_t)kt * 4096 + l15 * 64 + quad * 8;
#pragma unroll
        for (int ks = 0; ks < 2; ks++)
#pragma unroll
            for (int Mt = 0; Mt < 4; Mt++) {
                kh[ks][Mt] = *(const s16x8*)(khb + kbase + Mt * 1024 + ks * 32);
                kl[ks][Mt] = *(const s16x8*)(klb + kbase + Mt * 1024 + ks * 32);
            }
        const size_t vbase = (size_t)l15 * 1024 + kt * 64 + quad * 8;
#pragma unroll
        for (int ks = 0; ks < 2; ks++)
#pragma unroll
            for (int Mt = 0; Mt < 4; Mt++)
                vf[ks][Mt] = *(const s16x8*)(vbb + vbase + Mt * 16384 + ks * 32);

        // S = K^T Q (bf16x3)
        f32x4 S[4][2];
#pragma unroll
        for (int i = 0; i < 4; i++) { S[i][0] = (f32x4)0.0f; S[i][1] = (f32x4)0.0f; }
#pragma unroll
        for (int ks = 0; ks < 2; ks++)
#pragma unroll
            for (int Mt = 0; Mt < 4; Mt++)
#pragma unroll
                for (int Nt = 0; Nt < 2; Nt++) {
                    S[Mt][Nt] = MFMA16(kh[ks][Mt], qfh[Nt][ks], S[Mt][Nt]);
                    S[Mt][Nt] = MFMA16(kh[ks][Mt], qfl[Nt][ks], S[Mt][Nt]);
                    S[Mt][Nt] = MFMA16(kl[ks][Mt], qfh[Nt][ks], S[Mt][Nt]);
                }
        // Online softmax over nk per column m (stats span lanes l15+{0,16,32,48})
        float alpha[2];
#pragma unroll
        for (int Nt = 0; Nt < 2; Nt++) {
            float tm = -3.0e38f;
#pragma unroll
            for (int Mt = 0; Mt < 4; Mt++)
#pragma unroll
                for (int r = 0; r < 4; r++) tm = fmaxf(tm, S[Mt][Nt][r]);
            tm = fmaxf(tm, __shfl_xor(tm, 16));
            tm = fmaxf(tm, __shfl_xor(tm, 32));
            const float mnew = fmaxf(mrun[Nt], tm);
            alpha[Nt] = __expf(mrun[Nt] - mnew);
            float ts = 0.f;
#pragma unroll
            for (int Mt = 0; Mt < 4; Mt++)
#pragma unroll
                for (int r = 0; r < 4; r++) {
                    float p = __expf(S[Mt][Nt][r] - mnew);
                    S[Mt][Nt][r] = p;
                    ts += p;
                }
            ts += __shfl_xor(ts, 16);
            ts += __shfl_xor(ts, 32);
            lrun[Nt] = lrun[Nt] * alpha[Nt] + ts;
            mrun[Nt] = mnew;
        }
        // P (bf16) -> wave-private LDS rows [m][nk]; no barrier, lgkmcnt only
#pragma unroll
        for (int Mt = 0; Mt < 4; Mt++)
#pragma unroll
            for (int Nt = 0; Nt < 2; Nt++) {
                u16x4 pb;
#pragma unroll
                for (int r = 0; r < 4; r++) pb[r] = f2bf(S[Mt][Nt][r]);
                *(u16x4*)(Ps + (pr + Nt * 16) * 68 + Mt * 16 + quad * 4) = pb;
            }
        s16x8 pf[2][2];
#pragma unroll
        for (int Nt = 0; Nt < 2; Nt++)
#pragma unroll
            for (int ks = 0; ks < 2; ks++)
                pf[Nt][ks] = *(const s16x8*)(Ps + (pr + Nt * 16) * 68 + ks * 32 + quad * 8);
        // O = O*alpha + V @ P
#pragma unroll
        for (int Mt = 0; Mt < 4; Mt++)
#pragma unroll
            for (int Nt = 0; Nt < 2; Nt++) O[Mt][Nt] *= alpha[Nt];
#pragma unroll
        for (int ks = 0; ks < 2; ks++)
#pragma unroll
            for (int Mt = 0; Mt < 4; Mt++)
#pragma unroll
                for (int Nt = 0; Nt < 2; Nt++)
                    O[Mt][Nt] = MFMA16(vf[ks][Mt], pf[Nt][ks], O[Mt][Nt]);
    }

    // Epilogue: O /= l, split hi/lo into OL (wave-private rows), one barrier,
    // then coalesced gathered stores to ht planes [n][c].
    float linv[2] = {1.f / lrun[0], 1.f / lrun[1]};
#pragma unroll
    for (int Mt = 0; Mt < 4; Mt++)
#pragma unroll
        for (int Nt = 0; Nt < 2; Nt++) {
            u16x4 hi, lo;
#pragma unroll
            for (int r = 0; r < 4; r++) {
                u32 pk = splitpack(O[Mt][Nt][r] * linv[Nt]);
                hi[r] = (ushort)(pk >> 16);
                lo[r] = (ushort)pk;
            }
            const int m = (wv * 2 + Nt) * 16 + l15;
            *(u16x4*)(OLh + m * 72 + Mt * 16 + quad * 4) = hi;
            *(u16x4*)(OLl + m * 72 + Mt * 16 + quad * 4) = lo;
        }
    __syncthreads();
    const size_t ob = (size_t)b * 1024 + m0;
#pragma unroll
    for (int i = 0; i < 4; i++) {
        const int m = i * 32 + (t >> 3);
        const int u = t & 7;
        s16x8 vh2 = *(const s16x8*)(OLh + m * 72 + u * 8);
        s16x8 vl2 = *(const s16x8*)(OLl + m * 72 + u * 8);
        size_t go = (ob + m) * 512 + h * 64 + u * 8;
        *(s16x8*)(ht_h + go) = vh2;
        *(s16x8*)(ht_l + go) = vl2;
    }
}

// ---------------------------------------------------------------------------
extern "C" void kernel_launch(void* const* d_in, const int* in_sizes, int n_in,
                              void* d_out, int out_size, void* d_ws, size_t ws_size,
                              hipStream_t stream) {
    (void)in_sizes; (void)n_in; (void)out_size; (void)ws_size;
    const float* x      = (const float*)d_in[0];
    const float* w_qkv  = (const float*)d_in[1];
    const float* w_proj = (const float*)d_in[2];
    const float* b_proj = (const float*)d_in[3];
    float* out = (float*)d_out;

    // workspace layout (bytes), total 62,914,560 (< 67 MB proven safe).
    // ht aliases xt: xt is dead after gemm_qkv, ht written by attn after it.
    char* ws = (char*)d_ws;
    ushort* xt_h = (ushort*)(ws);                       // 8,388,608 (also ht_h)
    ushort* xt_l = (ushort*)(ws + 8388608);             // 8,388,608 (also ht_l)
    ushort* wq_h = (ushort*)(ws + 16777216);            // 1,572,864
    ushort* wq_l = (ushort*)(ws + 18350080);            // 1,572,864
    ushort* wp_h = (ushort*)(ws + 19922944);            //   524,288
    ushort* wp_l = (ushort*)(ws + 20447232);            //   524,288
    ushort* qhT  = (ushort*)(ws + 20971520);            // 8,388,608
    ushort* qlT  = (ushort*)(ws + 29360128);            // 8,388,608
    ushort* khT  = (ushort*)(ws + 37748736);            // 8,388,608
    ushort* klT  = (ushort*)(ws + 46137344);            // 8,388,608
    ushort* vbT  = (ushort*)(ws + 54525952);            // 8,388,608
    ushort* ht_h = xt_h;
    ushort* ht_l = xt_l;

    split_w<<<1024, 256, 0, stream>>>(w_qkv, w_proj, wq_h, wq_l, wp_h, wp_l);
    split_x<<<dim3(16, 8, 8), 256, 0, stream>>>(x, xt_h, xt_l);
    gemm_qkv<<<dim3(8, 12, 8), 256, 0, stream>>>(wq_h, wq_l, xt_h, xt_l,
                                                 qhT, qlT, khT, klT, vbT);
    attn_mfma<<<dim3(8, 64), 256, 0, stream>>>(qhT, qlT, khT, klT, vbT, ht_h, ht_l);
    gemm_proj<<<dim3(8, 4, 8), 256, 0, stream>>>(wp_h, wp_l, ht_h, ht_l, b_proj, out);
}